// Round 5
// baseline (177.758 us; speedup 1.0000x reference)
//
#include <hip/hip_runtime.h>

#define HW 224
#define HW2 50176            // 224*224
#define NCH 64
#define NPIX (4 * HW2)       // 200704 pixels total
#define CONV_OUT_ELEMS (4 * NCH * HW2)

typedef short bf16x8 __attribute__((ext_vector_type(8)));
typedef float f32x4 __attribute__((ext_vector_type(4)));

// fp32 -> bf16 round-to-nearest-even
__device__ __forceinline__ unsigned short f2bf(float f) {
    unsigned u = __float_as_uint(f);
    u += 0x7FFFu + ((u >> 16) & 1u);
    return (unsigned short)(u >> 16);
}

// ===========================================================================
// prep_all: blocks 0..783 convert x NCHW fp32 -> NHWC bf16 (256 pixels each;
// HW2 = 196*256 so blocks never straddle a batch). Block 784 permutes the
// weights into A-frag order AND zeroes hist (absorbs two tiny launches).
//
// Stage A: wave reads 1 KB contiguous float4 runs per inst; LDS tile is
// channel-major ls[c][pix] with row stride 260 (b64 read/write both hit each
// bank exactly 4x = the 512B minimum, conflict-free).
// Stage B: 8 b64 LDS reads -> 8x4 register transpose -> 16B NHWC stores in
// 128B contiguous runs.
// ===========================================================================
__global__ __launch_bounds__(256) void prep_all(
    const float* __restrict__ xf, const float* __restrict__ w,
    unsigned short* __restrict__ wbufA, unsigned short* __restrict__ xbf,
    float* __restrict__ hist)
{
    const int tid = threadIdx.x;

    if (blockIdx.x == 784) {
        // ---- zero hist (d_out tail is poisoned 0xAA each replay) ----
        for (int i = tid; i < NCH * 10; i += 256) hist[i] = 0.f;
        // ---- weight permute: o = (k*4+mg)*512 + lane*8 + j,
        //      value = w[co=mg*16+n][ci=(k&1)*32+q*8+j][tap=k>>1] ----
        for (int o = tid; o < 18 * 2048; o += 256) {
            const int j    = o & 7;
            const int lane = (o >> 3) & 63;
            const int n    = lane & 15;
            const int q    = lane >> 4;
            const int mg   = (o >> 9) & 3;
            const int k    = o >> 11;
            const int tap  = k >> 1;
            const int half = k & 1;
            const int ci   = half * 32 + q * 8 + j;
            const int co   = mg * 16 + n;
            wbufA[o] = f2bf(w[(co * 64 + ci) * 9 + tap]);
        }
        return;
    }

    __shared__ alignas(16) unsigned short ls[64 * 260];  // 33280 B

    const int g     = blockIdx.x;          // 0..783
    const int batch = g / 196;
    const int rem0  = (g - batch * 196) * 256;
    const int l     = tid & 63;
    const int wv    = tid >> 6;

    // ---- stage A: global fp32 -> LDS bf16, channel-major ----
    const float* base = xf + (size_t)batch * NCH * HW2 + rem0 + 4 * l;
#pragma unroll
    for (int t = 0; t < 16; ++t) {
        const int c = wv * 16 + t;
        const float4 v = *reinterpret_cast<const float4*>(base + (size_t)c * HW2);
        ushort4 u;
        u.x = f2bf(v.x); u.y = f2bf(v.y); u.z = f2bf(v.z); u.w = f2bf(v.w);
        *reinterpret_cast<ushort4*>(ls + c * 260 + 4 * l) = u;
    }
    __syncthreads();

    // ---- stage B: LDS -> NHWC 16B stores ----
    const int oct = tid & 7;
    const int p4  = tid >> 3;              // pixels 4*p4 .. +3
    ushort4 r[8];
#pragma unroll
    for (int j = 0; j < 8; ++j)
        r[j] = *reinterpret_cast<const ushort4*>(ls + (oct * 8 + j) * 260 + 4 * p4);

    unsigned short* dst = xbf + ((size_t)g * 256 + 4 * p4) * 64 + oct * 8;
#pragma unroll
    for (int k = 0; k < 4; ++k) {
        alignas(16) unsigned short o8[8];
        o8[0] = (&r[0].x)[k]; o8[1] = (&r[1].x)[k];
        o8[2] = (&r[2].x)[k]; o8[3] = (&r[3].x)[k];
        o8[4] = (&r[4].x)[k]; o8[5] = (&r[5].x)[k];
        o8[6] = (&r[6].x)[k]; o8[7] = (&r[7].x)[k];
        *reinterpret_cast<bf16x8*>(dst + k * 64) =
            *reinterpret_cast<const bf16x8*>(o8);
    }
}

// ---------------------------------------------------------------------------
// hist body: lane = column (coalesced), rolling 3-row window, honest fp32
// products. Packed 64-bit bin accumulator: 10 fields x 6 bits, max 28/field.
// ---------------------------------------------------------------------------
__device__ __forceinline__ void hist_body(
    const float* __restrict__ x, const float* __restrict__ w,
    float* __restrict__ hist, int rg, int c, int b, int tid, int* lh)
{
    if (tid < 10) lh[tid] = 0;
    __syncthreads();

    unsigned long long h64 = 0ull;
    const int col = tid;
    if (col < HW) {
        const float* plane = x + (size_t)(b * NCH + c) * HW2;
        float wk[9];
#pragma unroll
        for (int k = 0; k < 9; ++k) wk[k] = w[c * 9 + k];

        const bool vl = col > 0, vr = col < HW - 1;
        const int r0 = rg * 28;
        float u0, u1, u2, m0, m1, m2;
        if (r0 > 0) {
            const float* p = plane + (size_t)(r0 - 1) * HW + col;
            u0 = vl ? p[-1] : 0.f; u1 = p[0]; u2 = vr ? p[1] : 0.f;
        } else { u0 = u1 = u2 = 0.f; }
        {
            const float* p = plane + (size_t)r0 * HW + col;
            m0 = vl ? p[-1] : 0.f; m1 = p[0]; m2 = vr ? p[1] : 0.f;
        }

        for (int r = r0; r < r0 + 28; ++r) {
            float d0, d1, d2;
            if (r + 1 < HW) {
                const float* p = plane + (size_t)(r + 1) * HW + col;
                d0 = vl ? p[-1] : 0.f; d1 = p[0]; d2 = vr ? p[1] : 0.f;
            } else { d0 = d1 = d2 = 0.f; }

            int cnt = 0;
            cnt += (u0 * wk[0] != 0.f); cnt += (u1 * wk[1] != 0.f); cnt += (u2 * wk[2] != 0.f);
            cnt += (m0 * wk[3] != 0.f); cnt += (m1 * wk[4] != 0.f); cnt += (m2 * wk[5] != 0.f);
            cnt += (d0 * wk[6] != 0.f); cnt += (d1 * wk[7] != 0.f); cnt += (d2 * wk[8] != 0.f);
            const int z = 9 - cnt;
            h64 += 1ull << (z * 6);
            u0 = m0; u1 = m1; u2 = m2; m0 = d0; m1 = d1; m2 = d2;
        }
    }

#pragma unroll
    for (int k = 0; k < 10; ++k) {
        int v = (int)((h64 >> (6 * k)) & 63ull);
        v += __shfl_xor(v, 32); v += __shfl_xor(v, 16); v += __shfl_xor(v, 8);
        v += __shfl_xor(v, 4);  v += __shfl_xor(v, 2);  v += __shfl_xor(v, 1);
        if ((tid & 63) == 0 && v != 0) atomicAdd(&lh[k], v);
    }
    __syncthreads();
    if (tid < 10 && lh[tid] > 0)
        atomicAdd(&hist[c * 10 + tid], (float)lh[tid]);
}

// ===========================================================================
// conv_hist: blocks 0..783 = conv (round-4 conv_mfma_v2 body, unchanged);
// blocks 784..2831 = hist. Block-uniform branch; hist tail overlaps conv.
// ===========================================================================
__global__ __launch_bounds__(256, 3) void conv_hist(
    const unsigned short* __restrict__ xbf,
    const unsigned short* __restrict__ wbufA,
    const float* __restrict__ bias, float* __restrict__ y,
    const float* __restrict__ x, const float* __restrict__ w,
    float* __restrict__ hist)
{
    __shared__ alignas(16) unsigned short xs[340 * 64];  // 43520 B
    __shared__ int lh[10];

    const int tid = threadIdx.x;
    const int id  = blockIdx.x;

    if (id >= 784) {
        const int hid = id - 784;
        hist_body(x, w, hist, hid & 7, (hid >> 3) & 63, hid >> 9, tid, lh);
        return;
    }

    const int wv   = tid >> 6;
    const int lane = tid & 63;
    const int n    = lane & 15;
    const int q    = lane >> 4;
    const int c0   = (id % 7) * 32;
    const int r0   = ((id / 7) % 28) * 8;
    const int b    = id / 196;

    // ---- stage full halo tile: 340 pos x 8 blk 16B units, XOR swizzle ----
    for (int i = tid; i < 2720; i += 256) {
        const int pos = i >> 3;
        const int blk = i & 7;
        const int rr  = pos / 34;
        const int cc  = pos - rr * 34;
        const int gy  = r0 + rr - 1;
        const int gx  = c0 + cc - 1;
        const int phys = pos * 8 + (blk ^ (pos & 7));
        bf16x8 v = (bf16x8){0, 0, 0, 0, 0, 0, 0, 0};
        if ((unsigned)gy < (unsigned)HW && (unsigned)gx < (unsigned)HW)
            v = *reinterpret_cast<const bf16x8*>(
                xbf + ((size_t)(b * HW + gy) * HW + gx) * 64 + blk * 8);
        *reinterpret_cast<bf16x8*>(xs + phys * 8) = v;
    }
    __syncthreads();

    f32x4 acc[4][4];
#pragma unroll
    for (int mg = 0; mg < 4; ++mg)
#pragma unroll
        for (int g = 0; g < 4; ++g) acc[mg][g] = (f32x4){0.f, 0.f, 0.f, 0.f};

#pragma unroll
    for (int tap = 0; tap < 9; ++tap) {
        const int dh = tap / 3, dw = tap % 3;
#pragma unroll
        for (int half = 0; half < 2; ++half) {
            const int k = tap * 2 + half;
            bf16x8 a[4];
#pragma unroll
            for (int mg = 0; mg < 4; ++mg)
                a[mg] = *reinterpret_cast<const bf16x8*>(
                    wbufA + (k * 4 + mg) * 512 + lane * 8);
#pragma unroll
            for (int g = 0; g < 4; ++g) {
                const int pos = (2 * wv + (g >> 1) + dh) * 34
                              + (g & 1) * 16 + dw + n;
                const int phys = pos * 8 + ((half * 4 + q) ^ (pos & 7));
                const bf16x8 bf =
                    *reinterpret_cast<const bf16x8*>(xs + phys * 8);
#pragma unroll
                for (int mg = 0; mg < 4; ++mg)
                    acc[mg][g] = __builtin_amdgcn_mfma_f32_16x16x32_bf16(
                        a[mg], bf, acc[mg][g], 0, 0, 0);
            }
        }
    }

    // ---- epilogue: C/D col=lane&15 (spatial), row=q*4+reg (co) ----
#pragma unroll
    for (int g = 0; g < 4; ++g) {
        const int row = r0 + 2 * wv + (g >> 1);
        const int col = c0 + (g & 1) * 16 + n;
#pragma unroll
        for (int mg = 0; mg < 4; ++mg) {
#pragma unroll
            for (int rg = 0; rg < 4; ++rg) {
                const int co = mg * 16 + q * 4 + rg;
                y[((size_t)(b * NCH + co) * HW + row) * HW + col] =
                    acc[mg][g][rg] + bias[co];
            }
        }
    }
}

// ===========================================================================
// FALLBACK PATH (ws too small for xbf): round-2 kernels + standalone hist.
// ===========================================================================
__global__ void prep_weights_fb(const float* __restrict__ w,
                                unsigned short* __restrict__ wbuf) {
    const int o = blockIdx.x * 256 + threadIdx.x;
    if (o >= 2 * 9 * 4 * 16 * 32) return;
    const int ci = o & 31;
    const int t1 = o >> 5;
    const int co = t1 & 15;
    const int t2 = t1 >> 4;
    const int mg = t2 & 3;
    const int t3 = t2 >> 2;
    const int tap = t3 % 9;
    const int chunk = t3 / 9;
    wbuf[o] = f2bf(w[((mg * 16 + co) * 64 + (chunk * 32 + ci)) * 9 + tap]);
}

__global__ __launch_bounds__(256) void hist_fb(
    const float* __restrict__ x, const float* __restrict__ w,
    float* __restrict__ hist)
{
    __shared__ int lh[10];
    hist_body(x, w, hist, blockIdx.x, blockIdx.y, blockIdx.z, threadIdx.x, lh);
}

__global__ __launch_bounds__(256, 2) void conv_mfma_fb(
    const float* __restrict__ x, const unsigned short* __restrict__ wbuf,
    const float* __restrict__ bias, float* __restrict__ y)
{
    __shared__ alignas(16) unsigned short xs[340 * 32];
    const int tid  = threadIdx.x;
    const int wv   = tid >> 6;
    const int lane = tid & 63;
    const int n    = lane & 15;
    const int q    = lane >> 4;
    const int c0   = blockIdx.x * 32;
    const int r0   = blockIdx.y * 8;
    const int b    = blockIdx.z;

    f32x4 acc[4][4];
#pragma unroll
    for (int mg = 0; mg < 4; ++mg)
#pragma unroll
        for (int g = 0; g < 4; ++g) acc[mg][g] = (f32x4){0.f, 0.f, 0.f, 0.f};

    for (int chunk = 0; chunk < 2; ++chunk) {
        if (chunk) __syncthreads();
        const int ci0 = chunk * 32;
        for (int i = tid; i < 1360; i += 256) {
            const int ci8 = i / 340;
            const int pos = i - ci8 * 340;
            const int r   = pos / 34;
            const int c   = pos - r * 34;
            const int gy  = r0 + r - 1;
            const int gx  = c0 + c - 1;
            bf16x8 v;
            if ((unsigned)gy < (unsigned)HW && (unsigned)gx < (unsigned)HW) {
                const float* src =
                    x + ((size_t)(b * NCH + ci0 + ci8 * 8) * HW + gy) * HW + gx;
#pragma unroll
                for (int j = 0; j < 8; ++j) v[j] = (short)f2bf(src[(size_t)j * HW2]);
            } else {
#pragma unroll
                for (int j = 0; j < 8; ++j) v[j] = 0;
            }
            *reinterpret_cast<bf16x8*>(&xs[pos * 32 + ci8 * 8]) = v;
        }
        __syncthreads();

#pragma unroll
        for (int tap = 0; tap < 9; ++tap) {
            const int dh = tap / 3, dw = tap % 3;
            bf16x8 a[4];
#pragma unroll
            for (int mg = 0; mg < 4; ++mg) {
                const unsigned short* ap =
                    wbuf + ((chunk * 9 + tap) * 4 + mg) * 512 + n * 32 + q * 8;
                a[mg] = *reinterpret_cast<const bf16x8*>(ap);
            }
#pragma unroll
            for (int g = 0; g < 4; ++g) {
                const int rl = 2 * wv + (g >> 1) + dh;
                const int cl = (g & 1) * 16 + dw + n;
                const bf16x8 bf =
                    *reinterpret_cast<const bf16x8*>(&xs[(rl * 34 + cl) * 32 + q * 8]);
#pragma unroll
                for (int mg = 0; mg < 4; ++mg)
                    acc[mg][g] = __builtin_amdgcn_mfma_f32_16x16x32_bf16(
                        a[mg], bf, acc[mg][g], 0, 0, 0);
            }
        }
    }

#pragma unroll
    for (int g = 0; g < 4; ++g) {
        const int row = r0 + 2 * wv + (g >> 1);
        const int col = c0 + (g & 1) * 16 + n;
#pragma unroll
        for (int mg = 0; mg < 4; ++mg) {
#pragma unroll
            for (int rg = 0; rg < 4; ++rg) {
                const int co = mg * 16 + q * 4 + rg;
                y[((size_t)(b * NCH + co) * HW + row) * HW + col] =
                    acc[mg][g][rg] + bias[co];
            }
        }
    }
}

// ===========================================================================
extern "C" void kernel_launch(void* const* d_in, const int* in_sizes, int n_in,
                              void* d_out, int out_size, void* d_ws, size_t ws_size,
                              hipStream_t stream) {
    const float* x    = (const float*)d_in[0];
    const float* w    = (const float*)d_in[1];
    const float* bias = (const float*)d_in[2];
    float* y    = (float*)d_out;
    float* hist = (float*)d_out + CONV_OUT_ELEMS;

    const size_t NEED = 73728 + (size_t)NPIX * 64 * 2;  // 25,763,840 B
    if (ws_size >= NEED) {
        unsigned short* wbufA = (unsigned short*)d_ws;          // 73728 B
        unsigned short* xbf   = (unsigned short*)d_ws + 36864;  // NHWC bf16
        prep_all<<<785, 256, 0, stream>>>(x, w, wbufA, xbf, hist);
        conv_hist<<<784 + 2048, 256, 0, stream>>>(xbf, wbufA, bias, y,
                                                  x, w, hist);
    } else {
        unsigned short* wbuf = (unsigned short*)d_ws;
        hipMemsetAsync(hist, 0, 64 * 10 * sizeof(float), stream);
        prep_weights_fb<<<144, 256, 0, stream>>>(w, wbuf);
        conv_mfma_fb<<<dim3(7, 28, 4), 256, 0, stream>>>(x, wbuf, bias, y);
        hist_fb<<<dim3(8, 64, 4), 256, 0, stream>>>(x, w, hist);
    }
}

// Round 6
// 169.893 us; speedup vs baseline: 1.0463x; 1.0463x over previous
//
#include <hip/hip_runtime.h>

#define HW 224
#define HW2 50176            // 224*224
#define NCH 64
#define NPIX (4 * HW2)       // 200704 pixels total
#define CONV_OUT_ELEMS (4 * NCH * HW2)

typedef short bf16x8 __attribute__((ext_vector_type(8)));
typedef float f32x4 __attribute__((ext_vector_type(4)));

// fp32 -> bf16 round-to-nearest-even
__device__ __forceinline__ unsigned short f2bf(float f) {
    unsigned u = __float_as_uint(f);
    u += 0x7FFFu + ((u >> 16) & 1u);
    return (unsigned short)(u >> 16);
}

// ===========================================================================
// prep_all: blocks 0..783 convert x NCHW fp32 -> NHWC bf16 (256 pixels each;
// HW2 = 196*256 so blocks never straddle a batch). Block 784 permutes the
// weights into A-frag order AND zeroes hist.
//
// Stage A: wave reads contiguous 1 KB float4 runs; LDS tile channel-major
// ls[c][pix], row stride 260.
// Stage B: two 128-pixel halves (FULL 256-pixel coverage — round-5 bug was
// covering only half); per half: 8 b64 LDS reads -> 8x4 register transpose
// -> 16B NHWC stores in 128B contiguous runs.
// ===========================================================================
__global__ __launch_bounds__(256) void prep_all(
    const float* __restrict__ xf, const float* __restrict__ w,
    unsigned short* __restrict__ wbufA, unsigned short* __restrict__ xbf,
    float* __restrict__ hist)
{
    const int tid = threadIdx.x;

    if (blockIdx.x == 784) {
        for (int i = tid; i < NCH * 10; i += 256) hist[i] = 0.f;
        // weight permute: o = (k*4+mg)*512 + lane*8 + j,
        // value = w[co=mg*16+n][ci=(k&1)*32+q*8+j][tap=k>>1]
        for (int o = tid; o < 18 * 2048; o += 256) {
            const int j    = o & 7;
            const int lane = (o >> 3) & 63;
            const int n    = lane & 15;
            const int q    = lane >> 4;
            const int mg   = (o >> 9) & 3;
            const int k    = o >> 11;
            const int tap  = k >> 1;
            const int half = k & 1;
            const int ci   = half * 32 + q * 8 + j;
            const int co   = mg * 16 + n;
            wbufA[o] = f2bf(w[(co * 64 + ci) * 9 + tap]);
        }
        return;
    }

    __shared__ alignas(16) unsigned short ls[64 * 260];  // 33280 B

    const int g     = blockIdx.x;          // 0..783
    const int batch = g / 196;
    const int rem0  = (g - batch * 196) * 256;
    const int l     = tid & 63;
    const int wv    = tid >> 6;

    // ---- stage A: global fp32 -> LDS bf16, channel-major ----
    const float* base = xf + (size_t)batch * NCH * HW2 + rem0 + 4 * l;
#pragma unroll
    for (int t = 0; t < 16; ++t) {
        const int c = wv * 16 + t;
        const float4 v = *reinterpret_cast<const float4*>(base + (size_t)c * HW2);
        ushort4 u;
        u.x = f2bf(v.x); u.y = f2bf(v.y); u.z = f2bf(v.z); u.w = f2bf(v.w);
        *reinterpret_cast<ushort4*>(ls + c * 260 + 4 * l) = u;
    }
    __syncthreads();

    // ---- stage B: LDS -> NHWC 16B stores, TWO 128-pixel halves ----
    const int oct = tid & 7;
    const int p4  = tid >> 3;              // 0..31
#pragma unroll
    for (int half = 0; half < 2; ++half) {
        const int pix0 = half * 128 + 4 * p4;      // 0..252
        ushort4 r[8];
#pragma unroll
        for (int j = 0; j < 8; ++j)
            r[j] = *reinterpret_cast<const ushort4*>(
                ls + (oct * 8 + j) * 260 + pix0);

        unsigned short* dst = xbf + ((size_t)g * 256 + pix0) * 64 + oct * 8;
#pragma unroll
        for (int k = 0; k < 4; ++k) {
            alignas(16) unsigned short o8[8];
            o8[0] = (&r[0].x)[k]; o8[1] = (&r[1].x)[k];
            o8[2] = (&r[2].x)[k]; o8[3] = (&r[3].x)[k];
            o8[4] = (&r[4].x)[k]; o8[5] = (&r[5].x)[k];
            o8[6] = (&r[6].x)[k]; o8[7] = (&r[7].x)[k];
            *reinterpret_cast<bf16x8*>(dst + k * 64) =
                *reinterpret_cast<const bf16x8*>(o8);
        }
    }
}

// ===========================================================================
// Conv: implicit GEMM on NHWC bf16 input (round-4 verbatim, last known-good).
// ===========================================================================
__global__ __launch_bounds__(256, 3) void conv_mfma_v2(
    const unsigned short* __restrict__ xbf,
    const unsigned short* __restrict__ wbufA,
    const float* __restrict__ bias, float* __restrict__ y)
{
    __shared__ alignas(16) unsigned short xs[340 * 64];  // 43520 B

    const int tid  = threadIdx.x;
    const int wv   = tid >> 6;
    const int lane = tid & 63;
    const int n    = lane & 15;
    const int q    = lane >> 4;
    const int c0   = blockIdx.x * 32;
    const int r0   = blockIdx.y * 8;
    const int b    = blockIdx.z;

    // ---- stage full halo tile: 340 pos x 8 blk 16B units, XOR swizzle ----
    for (int i = tid; i < 2720; i += 256) {
        const int pos = i >> 3;
        const int blk = i & 7;
        const int rr  = pos / 34;
        const int cc  = pos - rr * 34;
        const int gy  = r0 + rr - 1;
        const int gx  = c0 + cc - 1;
        const int phys = pos * 8 + (blk ^ (pos & 7));
        bf16x8 v = (bf16x8){0, 0, 0, 0, 0, 0, 0, 0};
        if ((unsigned)gy < (unsigned)HW && (unsigned)gx < (unsigned)HW)
            v = *reinterpret_cast<const bf16x8*>(
                xbf + ((size_t)(b * HW + gy) * HW + gx) * 64 + blk * 8);
        *reinterpret_cast<bf16x8*>(xs + phys * 8) = v;
    }
    __syncthreads();

    f32x4 acc[4][4];
#pragma unroll
    for (int mg = 0; mg < 4; ++mg)
#pragma unroll
        for (int g = 0; g < 4; ++g) acc[mg][g] = (f32x4){0.f, 0.f, 0.f, 0.f};

#pragma unroll
    for (int tap = 0; tap < 9; ++tap) {
        const int dh = tap / 3, dw = tap % 3;
#pragma unroll
        for (int half = 0; half < 2; ++half) {
            const int k = tap * 2 + half;
            bf16x8 a[4];
#pragma unroll
            for (int mg = 0; mg < 4; ++mg)
                a[mg] = *reinterpret_cast<const bf16x8*>(
                    wbufA + (k * 4 + mg) * 512 + lane * 8);
#pragma unroll
            for (int g = 0; g < 4; ++g) {
                const int pos = (2 * wv + (g >> 1) + dh) * 34
                              + (g & 1) * 16 + dw + n;
                const int phys = pos * 8 + ((half * 4 + q) ^ (pos & 7));
                const bf16x8 bf =
                    *reinterpret_cast<const bf16x8*>(xs + phys * 8);
#pragma unroll
                for (int mg = 0; mg < 4; ++mg)
                    acc[mg][g] = __builtin_amdgcn_mfma_f32_16x16x32_bf16(
                        a[mg], bf, acc[mg][g], 0, 0, 0);
            }
        }
    }

    // ---- epilogue: C/D col=lane&15 (spatial), row=q*4+reg (co) ----
#pragma unroll
    for (int g = 0; g < 4; ++g) {
        const int row = r0 + 2 * wv + (g >> 1);
        const int col = c0 + (g & 1) * 16 + n;
#pragma unroll
        for (int mg = 0; mg < 4; ++mg) {
#pragma unroll
            for (int rg = 0; rg < 4; ++rg) {
                const int co = mg * 16 + q * 4 + rg;
                y[((size_t)(b * NCH + co) * HW + row) * HW + col] =
                    acc[mg][g][rg] + bias[co];
            }
        }
    }
}

// ---------------------------------------------------------------------------
// hist body: lane = column (coalesced), rolling 3-row window, honest fp32
// products. Packed 64-bit bin accumulator: 10 fields x 6 bits, max 28/field.
// ---------------------------------------------------------------------------
__device__ __forceinline__ void hist_body(
    const float* __restrict__ x, const float* __restrict__ w,
    float* __restrict__ hist, int rg, int c, int b, int tid, int* lh)
{
    if (tid < 10) lh[tid] = 0;
    __syncthreads();

    unsigned long long h64 = 0ull;
    const int col = tid;
    if (col < HW) {
        const float* plane = x + (size_t)(b * NCH + c) * HW2;
        float wk[9];
#pragma unroll
        for (int k = 0; k < 9; ++k) wk[k] = w[c * 9 + k];

        const bool vl = col > 0, vr = col < HW - 1;
        const int r0 = rg * 28;
        float u0, u1, u2, m0, m1, m2;
        if (r0 > 0) {
            const float* p = plane + (size_t)(r0 - 1) * HW + col;
            u0 = vl ? p[-1] : 0.f; u1 = p[0]; u2 = vr ? p[1] : 0.f;
        } else { u0 = u1 = u2 = 0.f; }
        {
            const float* p = plane + (size_t)r0 * HW + col;
            m0 = vl ? p[-1] : 0.f; m1 = p[0]; m2 = vr ? p[1] : 0.f;
        }

        for (int r = r0; r < r0 + 28; ++r) {
            float d0, d1, d2;
            if (r + 1 < HW) {
                const float* p = plane + (size_t)(r + 1) * HW + col;
                d0 = vl ? p[-1] : 0.f; d1 = p[0]; d2 = vr ? p[1] : 0.f;
            } else { d0 = d1 = d2 = 0.f; }

            int cnt = 0;
            cnt += (u0 * wk[0] != 0.f); cnt += (u1 * wk[1] != 0.f); cnt += (u2 * wk[2] != 0.f);
            cnt += (m0 * wk[3] != 0.f); cnt += (m1 * wk[4] != 0.f); cnt += (m2 * wk[5] != 0.f);
            cnt += (d0 * wk[6] != 0.f); cnt += (d1 * wk[7] != 0.f); cnt += (d2 * wk[8] != 0.f);
            const int z = 9 - cnt;
            h64 += 1ull << (z * 6);
            u0 = m0; u1 = m1; u2 = m2; m0 = d0; m1 = d1; m2 = d2;
        }
    }

#pragma unroll
    for (int k = 0; k < 10; ++k) {
        int v = (int)((h64 >> (6 * k)) & 63ull);
        v += __shfl_xor(v, 32); v += __shfl_xor(v, 16); v += __shfl_xor(v, 8);
        v += __shfl_xor(v, 4);  v += __shfl_xor(v, 2);  v += __shfl_xor(v, 1);
        if ((tid & 63) == 0 && v != 0) atomicAdd(&lh[k], v);
    }
    __syncthreads();
    if (tid < 10 && lh[tid] > 0)
        atomicAdd(&hist[c * 10 + tid], (float)lh[tid]);
}

__global__ __launch_bounds__(256) void hist_v3(
    const float* __restrict__ x, const float* __restrict__ w,
    float* __restrict__ hist)
{
    __shared__ int lh[10];
    hist_body(x, w, hist, blockIdx.x, blockIdx.y, blockIdx.z, threadIdx.x, lh);
}

// ===========================================================================
// FALLBACK PATH (ws too small for xbf): round-2 kernels + standalone hist.
// ===========================================================================
__global__ void prep_weights_fb(const float* __restrict__ w,
                                unsigned short* __restrict__ wbuf) {
    const int o = blockIdx.x * 256 + threadIdx.x;
    if (o >= 2 * 9 * 4 * 16 * 32) return;
    const int ci = o & 31;
    const int t1 = o >> 5;
    const int co = t1 & 15;
    const int t2 = t1 >> 4;
    const int mg = t2 & 3;
    const int t3 = t2 >> 2;
    const int tap = t3 % 9;
    const int chunk = t3 / 9;
    wbuf[o] = f2bf(w[((mg * 16 + co) * 64 + (chunk * 32 + ci)) * 9 + tap]);
}

__global__ __launch_bounds__(256, 2) void conv_mfma_fb(
    const float* __restrict__ x, const unsigned short* __restrict__ wbuf,
    const float* __restrict__ bias, float* __restrict__ y)
{
    __shared__ alignas(16) unsigned short xs[340 * 32];
    const int tid  = threadIdx.x;
    const int wv   = tid >> 6;
    const int lane = tid & 63;
    const int n    = lane & 15;
    const int q    = lane >> 4;
    const int c0   = blockIdx.x * 32;
    const int r0   = blockIdx.y * 8;
    const int b    = blockIdx.z;

    f32x4 acc[4][4];
#pragma unroll
    for (int mg = 0; mg < 4; ++mg)
#pragma unroll
        for (int g = 0; g < 4; ++g) acc[mg][g] = (f32x4){0.f, 0.f, 0.f, 0.f};

    for (int chunk = 0; chunk < 2; ++chunk) {
        if (chunk) __syncthreads();
        const int ci0 = chunk * 32;
        for (int i = tid; i < 1360; i += 256) {
            const int ci8 = i / 340;
            const int pos = i - ci8 * 340;
            const int r   = pos / 34;
            const int c   = pos - r * 34;
            const int gy  = r0 + r - 1;
            const int gx  = c0 + c - 1;
            bf16x8 v;
            if ((unsigned)gy < (unsigned)HW && (unsigned)gx < (unsigned)HW) {
                const float* src =
                    x + ((size_t)(b * NCH + ci0 + ci8 * 8) * HW + gy) * HW + gx;
#pragma unroll
                for (int j = 0; j < 8; ++j) v[j] = (short)f2bf(src[(size_t)j * HW2]);
            } else {
#pragma unroll
                for (int j = 0; j < 8; ++j) v[j] = 0;
            }
            *reinterpret_cast<bf16x8*>(&xs[pos * 32 + ci8 * 8]) = v;
        }
        __syncthreads();

#pragma unroll
        for (int tap = 0; tap < 9; ++tap) {
            const int dh = tap / 3, dw = tap % 3;
            bf16x8 a[4];
#pragma unroll
            for (int mg = 0; mg < 4; ++mg) {
                const unsigned short* ap =
                    wbuf + ((chunk * 9 + tap) * 4 + mg) * 512 + n * 32 + q * 8;
                a[mg] = *reinterpret_cast<const bf16x8*>(ap);
            }
#pragma unroll
            for (int g = 0; g < 4; ++g) {
                const int rl = 2 * wv + (g >> 1) + dh;
                const int cl = (g & 1) * 16 + dw + n;
                const bf16x8 bf =
                    *reinterpret_cast<const bf16x8*>(&xs[(rl * 34 + cl) * 32 + q * 8]);
#pragma unroll
                for (int mg = 0; mg < 4; ++mg)
                    acc[mg][g] = __builtin_amdgcn_mfma_f32_16x16x32_bf16(
                        a[mg], bf, acc[mg][g], 0, 0, 0);
            }
        }
    }

#pragma unroll
    for (int g = 0; g < 4; ++g) {
        const int row = r0 + 2 * wv + (g >> 1);
        const int col = c0 + (g & 1) * 16 + n;
#pragma unroll
        for (int mg = 0; mg < 4; ++mg) {
#pragma unroll
            for (int rg = 0; rg < 4; ++rg) {
                const int co = mg * 16 + q * 4 + rg;
                y[((size_t)(b * NCH + co) * HW + row) * HW + col] =
                    acc[mg][g][rg] + bias[co];
            }
        }
    }
}

// ===========================================================================
extern "C" void kernel_launch(void* const* d_in, const int* in_sizes, int n_in,
                              void* d_out, int out_size, void* d_ws, size_t ws_size,
                              hipStream_t stream) {
    const float* x    = (const float*)d_in[0];
    const float* w    = (const float*)d_in[1];
    const float* bias = (const float*)d_in[2];
    float* y    = (float*)d_out;
    float* hist = (float*)d_out + CONV_OUT_ELEMS;

    const size_t NEED = 73728 + (size_t)NPIX * 64 * 2;  // 25,763,840 B
    if (ws_size >= NEED) {
        unsigned short* wbufA = (unsigned short*)d_ws;          // 73728 B
        unsigned short* xbf   = (unsigned short*)d_ws + 36864;  // NHWC bf16
        prep_all<<<785, 256, 0, stream>>>(x, w, wbufA, xbf, hist);
        conv_mfma_v2<<<dim3(7, 28, 4), 256, 0, stream>>>(xbf, wbufA, bias, y);
        hist_v3<<<dim3(8, 64, 4), 256, 0, stream>>>(x, w, hist);
    } else {
        unsigned short* wbuf = (unsigned short*)d_ws;
        hipMemsetAsync(hist, 0, 64 * 10 * sizeof(float), stream);
        prep_weights_fb<<<144, 256, 0, stream>>>(w, wbuf);
        conv_mfma_fb<<<dim3(7, 28, 4), 256, 0, stream>>>(x, wbuf, bias, y);
        hist_v3<<<dim3(8, 64, 4), 256, 0, stream>>>(x, w, hist);
    }
}